// Round 1
// baseline (1786.847 us; speedup 1.0000x reference)
//
#include <hip/hip_runtime.h>
#include <hip/hip_bf16.h>

typedef unsigned short u16;
typedef __attribute__((ext_vector_type(8))) short s16x8;
typedef __attribute__((ext_vector_type(4))) float f32x4;

#define B_ 4
#define N_ 4096
#define C_ 1024
#define M_ (B_*N_)

__device__ __forceinline__ u16 f2bf(float f) {
  unsigned u = __builtin_bit_cast(unsigned, f);
  u = u + 0x7fffu + ((u >> 16) & 1u);
  return (u16)(u >> 16);
}
__device__ __forceinline__ float bf2f(u16 h) {
  unsigned u = ((unsigned)h) << 16;
  return __builtin_bit_cast(float, u);
}

// ---------------- kernel 0: fp32 -> bf16 precast of x and W ----------------
__global__ __launch_bounds__(256) void cast_kernel(
    const float* __restrict__ x, const float* __restrict__ w,
    u16* __restrict__ xb, u16* __restrict__ wb)
{
  const int NX4 = M_*C_/4;     // 4194304
  const int NW4 = 2048*C_/4;   // 524288
  int tid = blockIdx.x*256 + threadIdx.x;
  int stride = gridDim.x*256;
  for (int i = tid; i < NX4; i += stride) {
    f32x4 v = ((const f32x4*)x)[i];
    ushort4 o;
    o.x = f2bf(v[0]); o.y = f2bf(v[1]); o.z = f2bf(v[2]); o.w = f2bf(v[3]);
    ((ushort4*)xb)[i] = o;
  }
  for (int i = tid; i < NW4; i += stride) {
    f32x4 v = ((const f32x4*)w)[i];
    ushort4 o;
    o.x = f2bf(v[0]); o.y = f2bf(v[1]); o.z = f2bf(v[2]); o.w = f2bf(v[3]);
    ((ushort4*)wb)[i] = o;
  }
}

// ---------------- kernel 1: qk GEMM + bias + elu+1 -> q,k (bf16) ----------------
// C[m, n] = sum_k xb[m,k] * wb[n,k]   (B^T layout), m=16384, n=2048, k=1024
// 128x128 tile, BK=64, 4 waves (2x2), mfma_f32_16x16x32_bf16
__global__ __launch_bounds__(256) void gemm_kernel(
    const u16* __restrict__ xb, const u16* __restrict__ wb,
    const float* __restrict__ bqk,
    u16* __restrict__ qb, u16* __restrict__ kb)
{
  __shared__ __align__(16) unsigned char As[16384];  // 128 rows x 128B (64 bf16)
  __shared__ __align__(16) unsigned char Bs[16384];
  const int t = threadIdx.x;
  const int l = t & 63;
  const int w = t >> 6;
  const int wm = w >> 1, wn = w & 1;
  const int m0 = blockIdx.x * 128;
  const int n0 = blockIdx.y * 128;

  f32x4 acc[4][4];
  #pragma unroll
  for (int a = 0; a < 4; ++a)
    #pragma unroll
    for (int b = 0; b < 4; ++b) acc[a][b] = (f32x4){0.f,0.f,0.f,0.f};

  for (int kt = 0; kt < 1024; kt += 64) {
    __syncthreads();
    // stage A,B: linear LDS dest; inverse-swizzled global source (rule #21)
    #pragma unroll
    for (int i = 0; i < 4; ++i) {
      const int jc   = i*256 + t;                       // 16B chunk id 0..1023
      const int row  = jc >> 3;                         // 0..127
      const int colb = ((jc & 7) << 4) ^ ((row & 7) << 4); // source col byte
      const int cole = colb >> 1;                       // bf16 elem col
      const int ldsoff = (i*256 + w*64) * 16;           // wave-uniform base
      __builtin_amdgcn_global_load_lds(
        (const __attribute__((address_space(1))) void*)(xb + (size_t)(m0 + row)*1024 + kt + cole),
        (__attribute__((address_space(3))) void*)(As + ldsoff), 16, 0, 0);
      __builtin_amdgcn_global_load_lds(
        (const __attribute__((address_space(1))) void*)(wb + (size_t)(n0 + row)*1024 + kt + cole),
        (__attribute__((address_space(3))) void*)(Bs + ldsoff), 16, 0, 0);
    }
    __syncthreads();

    #pragma unroll
    for (int ks = 0; ks < 2; ++ks) {
      const int kbyte = ks*64 + ((l >> 4) << 4);
      s16x8 af[4], bff[4];
      #pragma unroll
      for (int mi = 0; mi < 4; ++mi) {
        const int r = wm*64 + mi*16 + (l & 15);
        af[mi] = *(const s16x8*)(As + r*128 + (kbyte ^ ((r & 7) << 4)));
      }
      #pragma unroll
      for (int ni = 0; ni < 4; ++ni) {
        const int r = wn*64 + ni*16 + (l & 15);
        bff[ni] = *(const s16x8*)(Bs + r*128 + (kbyte ^ ((r & 7) << 4)));
      }
      #pragma unroll
      for (int mi = 0; mi < 4; ++mi)
        #pragma unroll
        for (int ni = 0; ni < 4; ++ni)
          acc[mi][ni] = __builtin_amdgcn_mfma_f32_16x16x32_bf16(af[mi], bff[ni], acc[mi][ni], 0, 0, 0);
    }
  }

  // epilogue: bias + elu + 1, split to q / k buffers (block is uniformly q or k)
  #pragma unroll
  for (int ni = 0; ni < 4; ++ni) {
    const int col = n0 + wn*64 + ni*16 + (l & 15);   // 0..2047
    const float bias = bqk[col];
    u16* dst = (col < 1024) ? qb : kb;
    const int cc = col & 1023;
    #pragma unroll
    for (int mi = 0; mi < 4; ++mi) {
      #pragma unroll
      for (int j = 0; j < 4; ++j) {
        const int rowm = m0 + wm*64 + mi*16 + ((l >> 4) << 2) + j;
        float v = acc[mi][ni][j] + bias;
        v = (v > 0.f) ? (v + 1.f) : __expf(v);      // elu(v)+1
        dst[(size_t)rowm*1024 + cc] = f2bf(v);
      }
    }
  }
}

// ---------------- kernel 2: kv[b,h,d,e] and kmean[b,h,d] ----------------
// kv = (1/n) sum_n k_rope[n,d] * v[n,e];  kmean = mean_n k[n,d]
// grid 512 = (b,h) x 8 n-slices; thread t: d = t>>2, e-range = (t&3)*16..+16
__global__ __launch_bounds__(256) void kv_kernel(
    const u16* __restrict__ kb, const u16* __restrict__ xb,
    float* __restrict__ kv, float* __restrict__ kmean)
{
  const int blk = blockIdx.x;
  const int ns = blk & 7;
  const int bh = blk >> 3;             // 0..63
  const int b = bh >> 4, h = bh & 15;
  const int t = threadIdx.x;
  const int d = t >> 2;
  const int eg = t & 3;
  const int e0 = eg * 16;

  const int p = (h*64 + d) >> 1;       // rope pair index (constant per thread)
  const float theta = __powf(10000.f, -(float)p * (1.f/512.f));
  float sn, cn;
  __sincosf(theta, &sn, &cn);
  const float sgn = (d & 1) ? sn : -sn;   // kr = cn*k[d] + sgn*k[d^1]

  float kvacc[16];
  #pragma unroll
  for (int i = 0; i < 16; ++i) kvacc[i] = 0.f;
  float ksum = 0.f;

  const size_t base = ((size_t)b*4096 + ns*512) * 1024 + h*64;
  for (int n = 0; n < 512; ++n) {
    const size_t roff = base + (size_t)n * 1024;
    const float kd = bf2f(kb[roff + d]);
    const float kp = bf2f(kb[roff + (d ^ 1)]);
    const float kr = cn*kd + sgn*kp;
    ksum += kd;
    const s16x8 v0 = *(const s16x8*)(xb + roff + e0);
    const s16x8 v1 = *(const s16x8*)(xb + roff + e0 + 8);
    #pragma unroll
    for (int i = 0; i < 8; ++i) kvacc[i]     += kr * bf2f((u16)v0[i]);
    #pragma unroll
    for (int i = 0; i < 8; ++i) kvacc[8 + i] += kr * bf2f((u16)v1[i]);
  }
  const float inv_n = 1.f / 4096.f;
  float* dst = kv + ((size_t)bh*64 + d)*64 + e0;
  #pragma unroll
  for (int i = 0; i < 16; ++i) atomicAdd(dst + i, kvacc[i] * inv_n);
  if (eg == 0) atomicAdd(kmean + bh*64 + d, ksum * inv_n);
}

// ---------------- kernel 3: z, attn = q_rope @ kv * z, + depthwise-conv pe ----------------
// grid 256 = b x 64 n-tiles (64 rows each); thread t: n_l = t>>2, eg = t&3
__global__ __launch_bounds__(256) void out_kernel(
    const u16* __restrict__ qb, const float* __restrict__ kv,
    const float* __restrict__ kmean, const float* __restrict__ x,
    const float* __restrict__ lw, const float* __restrict__ lb,
    float* __restrict__ out)
{
  __shared__ float kms[1024];
  __shared__ __align__(16) float kvs[4096];
  __shared__ float qrs[64*65];          // +1 pad: conflict-free column reads
  __shared__ float cs_c[512];
  __shared__ float cs_s[512];

  const int t = threadIdx.x;
  const int n_l = t >> 2;
  const int eg = t & 3;
  const int blk = blockIdx.x;
  const int b = blk >> 6;
  const int nt = blk & 63;
  const int n = nt*64 + n_l;
  const size_t rowx = ((size_t)b*4096 + n) * 1024;

  for (int i = t; i < 1024; i += 256) kms[i] = kmean[b*1024 + i];
  for (int i = t; i < 512; i += 256) {
    const float theta = __powf(10000.f, -(float)i * (1.f/512.f));
    float sn, cn;
    __sincosf(theta, &sn, &cn);
    cs_c[i] = cn; cs_s[i] = sn;
  }

  for (int h = 0; h < 16; ++h) {
    __syncthreads();   // protects kvs/qrs reuse + first-iter table init
    const float* kvsrc = kv + (size_t)(b*16 + h) * 4096;
    for (int i = t; i < 1024; i += 256)
      ((f32x4*)kvs)[i] = ((const f32x4*)kvsrc)[i];

    // 16 q values for this thread's d-quarter
    const u16* qrow = qb + rowx + h*64 + eg*16;
    const s16x8 q0 = *(const s16x8*)qrow;
    const s16x8 q1 = *(const s16x8*)(qrow + 8);
    float qf[16];
    #pragma unroll
    for (int i = 0; i < 8; ++i) { qf[i] = bf2f((u16)q0[i]); qf[8+i] = bf2f((u16)q1[i]); }

    // z = 1/(q . kmean + 1e-6), 4-lane-group reduce
    float zp = 0.f;
    #pragma unroll
    for (int i = 0; i < 16; ++i) zp += qf[i] * kms[h*64 + eg*16 + i];
    zp += __shfl_xor(zp, 1);
    zp += __shfl_xor(zp, 2);
    const float z = 1.f / (zp + 1e-6f);

    // rope the 16 q's into shared (pairs are within the 16-chunk)
    #pragma unroll
    for (int i = 0; i < 16; i += 2) {
      const int dd = eg*16 + i;
      const int p = h*32 + (dd >> 1);
      const float cn = cs_c[p], sn = cs_s[p];
      qrs[n_l*65 + dd]     = cn*qf[i] - sn*qf[i+1];
      qrs[n_l*65 + dd + 1] = sn*qf[i] + cn*qf[i+1];
    }
    __syncthreads();

    // attn[e] = sum_d q_rope[d] * kv[d][e]
    f32x4 acc4[4];
    #pragma unroll
    for (int c2 = 0; c2 < 4; ++c2) acc4[c2] = (f32x4){0.f,0.f,0.f,0.f};
    for (int dd = 0; dd < 64; ++dd) {
      const float qr = qrs[n_l*65 + dd];
      const f32x4* kv4 = (const f32x4*)(kvs + dd*64 + eg*16);
      #pragma unroll
      for (int c2 = 0; c2 < 4; ++c2) acc4[c2] += qr * kv4[c2];
    }

    // pe (depthwise conv, corr. no flip) + write fp32
    const int ch0 = h*64 + eg*16;
    #pragma unroll
    for (int g = 0; g < 4; ++g) {
      const int ch = ch0 + g*4;
      f32x4 xm = (f32x4){0.f,0.f,0.f,0.f}, xp = (f32x4){0.f,0.f,0.f,0.f};
      const f32x4 xc = *(const f32x4*)(x + rowx + ch);
      if (n > 0)    xm = *(const f32x4*)(x + rowx - 1024 + ch);
      if (n < 4095) xp = *(const f32x4*)(x + rowx + 1024 + ch);
      f32x4 o;
      #pragma unroll
      for (int j = 0; j < 4; ++j) {
        const int c = ch + j;
        const float pe = lb[c] + xm[j]*lw[c*3] + xc[j]*lw[c*3+1] + xp[j]*lw[c*3+2];
        o[j] = acc4[g][j]*z + pe;
      }
      *(f32x4*)(out + rowx + ch) = o;
    }
  }
}

extern "C" void kernel_launch(void* const* d_in, const int* in_sizes, int n_in,
                              void* d_out, int out_size, void* d_ws, size_t ws_size,
                              hipStream_t stream) {
  const float* x   = (const float*)d_in[0];
  const float* Wqk = (const float*)d_in[1];
  const float* bqk = (const float*)d_in[2];
  const float* lw  = (const float*)d_in[3];
  const float* lb  = (const float*)d_in[4];
  float* out = (float*)d_out;

  char* ws = (char*)d_ws;
  u16* xb = (u16*)(ws);                       // 33.55 MB  x bf16
  u16* qb = (u16*)(ws + 33554432ull);         // 33.55 MB  q bf16
  u16* kb = (u16*)(ws + 67108864ull);         // 33.55 MB  k bf16
  u16* wb = (u16*)(ws + 100663296ull);        //  4.19 MB  W bf16
  float* kv = (float*)(ws + 104857600ull);    //  1.00 MB  fp32
  float* km = (float*)(ws + 105906176ull);    // 16 KB     fp32

  // kv/kmean are atomically accumulated -> zero every launch (capture-safe)
  hipMemsetAsync(ws + 104857600ull, 0, 1048576ull + 16384ull, stream);
  hipLaunchKernelGGL(cast_kernel, dim3(2048), dim3(256), 0, stream, x, Wqk, xb, wb);
  hipLaunchKernelGGL(gemm_kernel, dim3(128, 16), dim3(256), 0, stream, xb, wb, bqk, qb, kb);
  hipLaunchKernelGGL(kv_kernel, dim3(512), dim3(256), 0, stream, kb, xb, kv, km);
  hipLaunchKernelGGL(out_kernel, dim3(256), dim3(256), 0, stream, qb, kv, km, x, lw, lb, out);
}

// Round 2
// 1756.221 us; speedup vs baseline: 1.0174x; 1.0174x over previous
//
#include <hip/hip_runtime.h>
#include <hip/hip_bf16.h>

typedef unsigned short u16;
typedef __attribute__((ext_vector_type(8))) short s16x8;
typedef __attribute__((ext_vector_type(4))) float f32x4;

#define B_ 4
#define N_ 4096
#define C_ 1024
#define M_ (B_*N_)

__device__ __forceinline__ u16 f2bf(float f) {
  unsigned u = __builtin_bit_cast(unsigned, f);
  u = u + 0x7fffu + ((u >> 16) & 1u);
  return (u16)(u >> 16);
}
__device__ __forceinline__ float bf2f(u16 h) {
  unsigned u = ((unsigned)h) << 16;
  return __builtin_bit_cast(float, u);
}

// ---------------- kernel 0: fp32 -> bf16 precast of x and W ----------------
__global__ __launch_bounds__(256) void cast_kernel(
    const float* __restrict__ x, const float* __restrict__ w,
    u16* __restrict__ xb, u16* __restrict__ wb)
{
  const int NX4 = M_*C_/4;     // 4194304
  const int NW4 = 2048*C_/4;   // 524288
  int tid = blockIdx.x*256 + threadIdx.x;
  int stride = gridDim.x*256;
  for (int i = tid; i < NX4; i += stride) {
    f32x4 v = ((const f32x4*)x)[i];
    ushort4 o;
    o.x = f2bf(v[0]); o.y = f2bf(v[1]); o.z = f2bf(v[2]); o.w = f2bf(v[3]);
    ((ushort4*)xb)[i] = o;
  }
  for (int i = tid; i < NW4; i += stride) {
    f32x4 v = ((const f32x4*)w)[i];
    ushort4 o;
    o.x = f2bf(v[0]); o.y = f2bf(v[1]); o.z = f2bf(v[2]); o.w = f2bf(v[3]);
    ((ushort4*)wb)[i] = o;
  }
}

// ---------------- kernel 1: qk GEMM + bias + elu+1 -> q,k (bf16) ----------------
// C[m, n] = sum_k xb[m,k] * wb[n,k]   (B^T layout), m=16384, n=2048, k=1024
// 128x128 tile, BK=64, 4 waves (2x2), mfma_f32_16x16x32_bf16
__global__ __launch_bounds__(256) void gemm_kernel(
    const u16* __restrict__ xb, const u16* __restrict__ wb,
    const float* __restrict__ bqk,
    u16* __restrict__ qb, u16* __restrict__ kb)
{
  __shared__ __align__(16) unsigned char As[16384];  // 128 rows x 128B (64 bf16)
  __shared__ __align__(16) unsigned char Bs[16384];
  const int t = threadIdx.x;
  const int l = t & 63;
  const int w = t >> 6;
  const int wm = w >> 1, wn = w & 1;
  const int m0 = blockIdx.x * 128;
  const int n0 = blockIdx.y * 128;

  f32x4 acc[4][4];
  #pragma unroll
  for (int a = 0; a < 4; ++a)
    #pragma unroll
    for (int b = 0; b < 4; ++b) acc[a][b] = (f32x4){0.f,0.f,0.f,0.f};

  for (int kt = 0; kt < 1024; kt += 64) {
    __syncthreads();
    // stage A,B: linear LDS dest; inverse-swizzled global source (rule #21)
    #pragma unroll
    for (int i = 0; i < 4; ++i) {
      const int jc   = i*256 + t;                       // 16B chunk id 0..1023
      const int row  = jc >> 3;                         // 0..127
      const int colb = ((jc & 7) << 4) ^ ((row & 7) << 4); // source col byte
      const int cole = colb >> 1;                       // bf16 elem col
      const int ldsoff = (i*256 + w*64) * 16;           // wave-uniform base
      __builtin_amdgcn_global_load_lds(
        (const __attribute__((address_space(1))) void*)(xb + (size_t)(m0 + row)*1024 + kt + cole),
        (__attribute__((address_space(3))) void*)(As + ldsoff), 16, 0, 0);
      __builtin_amdgcn_global_load_lds(
        (const __attribute__((address_space(1))) void*)(wb + (size_t)(n0 + row)*1024 + kt + cole),
        (__attribute__((address_space(3))) void*)(Bs + ldsoff), 16, 0, 0);
    }
    __syncthreads();

    #pragma unroll
    for (int ks = 0; ks < 2; ++ks) {
      const int kbyte = ks*64 + ((l >> 4) << 4);
      s16x8 af[4], bff[4];
      #pragma unroll
      for (int mi = 0; mi < 4; ++mi) {
        const int r = wm*64 + mi*16 + (l & 15);
        af[mi] = *(const s16x8*)(As + r*128 + (kbyte ^ ((r & 7) << 4)));
      }
      #pragma unroll
      for (int ni = 0; ni < 4; ++ni) {
        const int r = wn*64 + ni*16 + (l & 15);
        bff[ni] = *(const s16x8*)(Bs + r*128 + (kbyte ^ ((r & 7) << 4)));
      }
      #pragma unroll
      for (int mi = 0; mi < 4; ++mi)
        #pragma unroll
        for (int ni = 0; ni < 4; ++ni)
          acc[mi][ni] = __builtin_amdgcn_mfma_f32_16x16x32_bf16(af[mi], bff[ni], acc[mi][ni], 0, 0, 0);
    }
  }

  // epilogue: bias + elu + 1, split to q / k buffers (block is uniformly q or k)
  #pragma unroll
  for (int ni = 0; ni < 4; ++ni) {
    const int col = n0 + wn*64 + ni*16 + (l & 15);   // 0..2047
    const float bias = bqk[col];
    u16* dst = (col < 1024) ? qb : kb;
    const int cc = col & 1023;
    #pragma unroll
    for (int mi = 0; mi < 4; ++mi) {
      #pragma unroll
      for (int j = 0; j < 4; ++j) {
        const int rowm = m0 + wm*64 + mi*16 + ((l >> 4) << 2) + j;
        float v = acc[mi][ni][j] + bias;
        v = (v > 0.f) ? (v + 1.f) : __expf(v);      // elu(v)+1
        dst[(size_t)rowm*1024 + cc] = f2bf(v);
      }
    }
  }
}

// ---------------- kernel 2: kv[b,h,d,e] and kmean[b,h,d] ----------------
// kv = (1/n) sum_n k_rope[n,d] * v[n,e];  kmean = mean_n k[n,d]
// grid 512 = (b,h) x 8 n-slices; thread t: d = t>>2, e-range = (t&3)*16..+16
__global__ __launch_bounds__(256) void kv_kernel(
    const u16* __restrict__ kb, const u16* __restrict__ xb,
    float* __restrict__ kv, float* __restrict__ kmean)
{
  const int blk = blockIdx.x;
  const int ns = blk & 7;
  const int bh = blk >> 3;             // 0..63
  const int b = bh >> 4, h = bh & 15;
  const int t = threadIdx.x;
  const int d = t >> 2;
  const int eg = t & 3;
  const int e0 = eg * 16;

  const int p = (h*64 + d) >> 1;       // rope pair index (constant per thread)
  const float theta = __powf(10000.f, -(float)p * (1.f/512.f));
  float sn, cn;
  __sincosf(theta, &sn, &cn);
  const float sgn = (d & 1) ? sn : -sn;   // kr = cn*k[d] + sgn*k[d^1]

  float kvacc[16];
  #pragma unroll
  for (int i = 0; i < 16; ++i) kvacc[i] = 0.f;
  float ksum = 0.f;

  const size_t base = ((size_t)b*4096 + ns*512) * 1024 + h*64;
  for (int n = 0; n < 512; ++n) {
    const size_t roff = base + (size_t)n * 1024;
    const float kd = bf2f(kb[roff + d]);
    const float kp = bf2f(kb[roff + (d ^ 1)]);
    const float kr = cn*kd + sgn*kp;
    ksum += kd;
    const s16x8 v0 = *(const s16x8*)(xb + roff + e0);
    const s16x8 v1 = *(const s16x8*)(xb + roff + e0 + 8);
    #pragma unroll
    for (int i = 0; i < 8; ++i) kvacc[i]     += kr * bf2f((u16)v0[i]);
    #pragma unroll
    for (int i = 0; i < 8; ++i) kvacc[8 + i] += kr * bf2f((u16)v1[i]);
  }
  const float inv_n = 1.f / 4096.f;
  float* dst = kv + ((size_t)bh*64 + d)*64 + e0;
  #pragma unroll
  for (int i = 0; i < 16; ++i) atomicAdd(dst + i, kvacc[i] * inv_n);
  if (eg == 0) atomicAdd(kmean + bh*64 + d, ksum * inv_n);
}

// ---------------- kernel 3: z, attn = q_rope @ kv * z, + depthwise-conv pe ----------------
// grid (64 ntiles, 16 h, 4 b) = 4096 blocks; block = 256 threads = 64 rows x 4 e-groups.
// No per-h loop -> small live state, no spills. d-chunk exchange via shfl within
// 4-lane groups; kv tile + lepe weights staged in LDS.
__global__ __launch_bounds__(256) void out_kernel(
    const u16* __restrict__ qb, const float* __restrict__ kv,
    const float* __restrict__ kmean, const float* __restrict__ x,
    const float* __restrict__ lw, const float* __restrict__ lb,
    float* __restrict__ out)
{
  __shared__ __align__(16) float kvs[4096];   // kv[d][e] for this (b,h): 16 KB
  __shared__ float kms[64];
  __shared__ float csc[32], css[32];
  __shared__ float lws[64*3], lbs[64];

  const int t  = threadIdx.x;
  const int nt = blockIdx.x;
  const int h  = blockIdx.y;
  const int b  = blockIdx.z;

  // stage kv tile (16 KB), kmean slice, rope table, lepe weights
  const float* kvsrc = kv + (size_t)(b*16 + h) * 4096;
  #pragma unroll
  for (int i = 0; i < 4; ++i)
    ((f32x4*)kvs)[i*256 + t] = ((const f32x4*)kvsrc)[i*256 + t];
  if (t < 64)  kms[t] = kmean[(b*16 + h)*64 + t];
  if (t < 32) {
    const float theta = __powf(10000.f, -(float)(h*32 + t) * (1.f/512.f));
    float sn, cn;
    __sincosf(theta, &sn, &cn);
    csc[t] = cn; css[t] = sn;
  }
  if (t >= 64 && t < 256) {
    const int i = t - 64;                 // 0..191
    lws[i] = lw[h*192 + i];               // lw[(h*64+ch)*3 + j]
  }
  if (t >= 32 && t < 96) lbs[t-32] = lb[h*64 + (t-32)];
  __syncthreads();

  const int r  = t >> 2;                  // row 0..63
  const int eg = t & 3;                   // e/d quarter
  const int n  = nt*64 + r;               // 0..4095 within batch b
  const size_t rowx = ((size_t)b*4096 + n) * 1024;

  // q chunk: 16 bf16
  const u16* qrow = qb + rowx + h*64 + eg*16;
  const s16x8 q0 = *(const s16x8*)qrow;
  const s16x8 q1 = *(const s16x8*)(qrow + 8);
  float qf[16];
  #pragma unroll
  for (int i = 0; i < 8; ++i) { qf[i] = bf2f((u16)q0[i]); qf[8+i] = bf2f((u16)q1[i]); }

  // z = 1/(q . kmean + 1e-6): 4-lane-group reduce
  float zp = 0.f;
  #pragma unroll
  for (int i = 0; i < 16; ++i) zp += qf[i] * kms[eg*16 + i];
  zp += __shfl_xor(zp, 1);
  zp += __shfl_xor(zp, 2);
  const float z = 1.f / (zp + 1e-6f);

  // rope q in registers (pairs are inside the 16-chunk; eg*16 is even)
  float qr[16];
  #pragma unroll
  for (int i = 0; i < 16; i += 2) {
    const int p = eg*8 + (i >> 1);        // local pair index within head
    const float cn = csc[p], sn = css[p];
    qr[i]   = cn*qf[i]   - sn*qf[i+1];
    qr[i+1] = sn*qf[i]   + cn*qf[i+1];
  }

  // attn[e0..e0+15] = sum_d qr_full[d] * kv[d][e]; full d via shfl_xor over 4-lane group
  f32x4 acc4[4];
  #pragma unroll
  for (int c = 0; c < 4; ++c) acc4[c] = (f32x4){0.f,0.f,0.f,0.f};
  #pragma unroll
  for (int pass = 0; pass < 4; ++pass) {
    const int dc = (eg ^ pass) * 16;      // d-chunk held by partner lane
    #pragma unroll
    for (int i = 0; i < 16; ++i) {
      const float qd = __shfl_xor(qr[i], pass);
      const f32x4* kvrow = (const f32x4*)(kvs + (dc + i)*64 + eg*16);
      #pragma unroll
      for (int c = 0; c < 4; ++c) acc4[c] += qd * kvrow[c];
    }
  }

  // pe (depthwise 3-tap conv on x) + final write
  #pragma unroll
  for (int g = 0; g < 4; ++g) {
    const int che = eg*16 + g*4;          // channel offset within head, 0..63
    const int ch  = h*64 + che;           // global channel
    f32x4 xm = (f32x4){0.f,0.f,0.f,0.f}, xp = (f32x4){0.f,0.f,0.f,0.f};
    const f32x4 xc = *(const f32x4*)(x + rowx + ch);
    if (n > 0)    xm = *(const f32x4*)(x + rowx - 1024 + ch);
    if (n < 4095) xp = *(const f32x4*)(x + rowx + 1024 + ch);
    f32x4 o;
    #pragma unroll
    for (int j = 0; j < 4; ++j) {
      const int cl = che + j;
      const float pe = lbs[cl] + xm[j]*lws[cl*3] + xc[j]*lws[cl*3+1] + xp[j]*lws[cl*3+2];
      o[j] = acc4[g][j]*z + pe;
    }
    *(f32x4*)(out + rowx + ch) = o;
  }
}

extern "C" void kernel_launch(void* const* d_in, const int* in_sizes, int n_in,
                              void* d_out, int out_size, void* d_ws, size_t ws_size,
                              hipStream_t stream) {
  const float* x   = (const float*)d_in[0];
  const float* Wqk = (const float*)d_in[1];
  const float* bqk = (const float*)d_in[2];
  const float* lw  = (const float*)d_in[3];
  const float* lb  = (const float*)d_in[4];
  float* out = (float*)d_out;

  char* ws = (char*)d_ws;
  u16* xb = (u16*)(ws);                       // 33.55 MB  x bf16
  u16* qb = (u16*)(ws + 33554432ull);         // 33.55 MB  q bf16
  u16* kb = (u16*)(ws + 67108864ull);         // 33.55 MB  k bf16
  u16* wb = (u16*)(ws + 100663296ull);        //  4.19 MB  W bf16
  float* kv = (float*)(ws + 104857600ull);    //  1.00 MB  fp32
  float* km = (float*)(ws + 105906176ull);    // 16 KB     fp32

  // kv/kmean are atomically accumulated -> zero every launch (capture-safe)
  hipMemsetAsync(ws + 104857600ull, 0, 1048576ull + 16384ull, stream);
  hipLaunchKernelGGL(cast_kernel, dim3(2048), dim3(256), 0, stream, x, Wqk, xb, wb);
  hipLaunchKernelGGL(gemm_kernel, dim3(128, 16), dim3(256), 0, stream, xb, wb, bqk, qb, kb);
  hipLaunchKernelGGL(kv_kernel, dim3(512), dim3(256), 0, stream, kb, xb, kv, km);
  hipLaunchKernelGGL(out_kernel, dim3(64, 16, 4), dim3(256), 0, stream, qb, kv, km, x, lw, lb, out);
}